// Round 2
// baseline (577.878 us; speedup 1.0000x reference)
//
#include <hip/hip_runtime.h>
#include <hip/hip_bf16.h>
#include <math.h>

#define BB 4
#define TT 200
#define UU 101
#define VV 1024
#define NCELL (BB*TT*UU)   // 80800

// Diagonal-major staging layout (written by lse_kernel, read by alpha_kernel):
//   blankD[b][d][u] = blank_lp(t=d-u, u)            rows d in [0,299], stride 102 (float2-aligned)
//   labD  [b][d][u] = label_lp(t=d-u, u-1)          rows d in [0,300], stride 102
// so alpha's per-diagonal reads are contiguous in u (coalesced float2).
#define DSTRIDE 102
#define BROWS 300
#define LROWS 301

__device__ __forceinline__ float f4max(const float4& v) {
    return fmaxf(fmaxf(v.x, v.y), fmaxf(v.z, v.w));
}
__device__ __forceinline__ float f4comp(const float4& v, int c) {
    switch (c & 3) { case 0: return v.x; case 1: return v.y; case 2: return v.z; default: return v.w; }
}

// Kernel 1: one 64-lane wave per (b,t,u) cell. LSE over V=1024; writes blank/label
// log-probs into the diagonal-major staging buffers.
__global__ __launch_bounds__(256) void lse_kernel(
        const float* __restrict__ logits,
        const int*   __restrict__ labels,     // [B, U-1]
        float* __restrict__ blankD,           // [B][300][102]
        float* __restrict__ labD) {           // [B][301][102]
    const int wave = threadIdx.x >> 6;
    const int lane = threadIdx.x & 63;
    const int cell = blockIdx.x * 4 + wave;
    if (cell >= NCELL) return;
    const int b   = cell / (TT * UU);
    const int rem = cell % (TT * UU);
    const int t   = rem / UU;
    const int u   = rem % UU;

    const float4* src = (const float4*)(logits + (size_t)cell * VV);
    float4 x0 = src[lane];
    float4 x1 = src[lane + 64];
    float4 x2 = src[lane + 128];
    float4 x3 = src[lane + 192];

    float m = fmaxf(fmaxf(f4max(x0), f4max(x1)), fmaxf(f4max(x2), f4max(x3)));
    #pragma unroll
    for (int off = 32; off; off >>= 1) m = fmaxf(m, __shfl_xor(m, off));

    float s = 0.f;
    s += __expf(x0.x - m) + __expf(x0.y - m) + __expf(x0.z - m) + __expf(x0.w - m);
    s += __expf(x1.x - m) + __expf(x1.y - m) + __expf(x1.z - m) + __expf(x1.w - m);
    s += __expf(x2.x - m) + __expf(x2.y - m) + __expf(x2.z - m) + __expf(x2.w - m);
    s += __expf(x3.x - m) + __expf(x3.y - m) + __expf(x3.z - m) + __expf(x3.w - m);
    #pragma unroll
    for (int off = 32; off; off >>= 1) s += __shfl_xor(s, off);

    const float lse = m + __logf(s);

    if (lane == 0)
        blankD[(size_t)b * BROWS * DSTRIDE + (t + u) * DSTRIDE + u] = x0.x - lse;

    if (u < UU - 1) {
        int l = labels[b * (UU - 1) + u];
        l = min(max(l, 0), VV - 1);
        const int lane_l = (l >> 2) & 63;
        if (lane == lane_l) {
            const int j = l >> 8;      // which float4 (0..3)
            const int c = l & 3;       // component
            float val = (j == 0) ? f4comp(x0, c) : (j == 1) ? f4comp(x1, c)
                      : (j == 2) ? f4comp(x2, c) : f4comp(x3, c);
            // label emitted into cell (t, u+1), which lies on diagonal t+u+1
            labD[(size_t)b * LROWS * DSTRIDE + (t + u + 1) * DSTRIDE + (u + 1)] = val - lse;
        }
    }
}

// Kernel 2: one 64-lane wave per batch. Lane i owns columns 2i, 2i+1.
// No barriers; one shfl_up per diagonal; coalesced float2 diagonal loads,
// software-prefetched 4 diagonals ahead.
__global__ __launch_bounds__(64) void alpha_kernel(
        const float* __restrict__ blankD,
        const float* __restrict__ labD,
        const int*   __restrict__ lab_lens,   // [B]
        const int*   __restrict__ attn,       // [B, T]
        float* __restrict__ loss_b,           // [B]
        int*   __restrict__ valid_b) {        // [B]
    const int b = blockIdx.x;
    const int lane = threadIdx.x;

    __shared__ float s_loss;
    if (lane == 0) s_loss = 0.f;

    // input length = clip(sum(attn[b,:]), 1, T)
    int acc = 0;
    for (int i = lane; i < TT; i += 64) acc += attn[b * TT + i];
    #pragma unroll
    for (int off = 32; off; off >>= 1) acc += __shfl_xor(acc, off);
    const int inlen = min(max(acc, 1), TT);
    const int tmax = inlen - 1;
    int lab = lab_lens[b];
    lab = min(max(lab, 0), UU - 1);
    const int ndiag = tmax + lab + 1;   // target cell (tmax, lab) computed at d = ndiag-1

    const float* blb = blankD + (size_t)b * BROWS * DSTRIDE;
    const float* llb = labD   + (size_t)b * LROWS * DSTRIDE;

    const int c0 = 2 * lane;
    const int c1 = 2 * lane + 1;
    const int cc = min(c0, 100);        // clamp load column (lanes 51..63 inactive)

    auto loadB = [&](int d) -> float2 {
        return *(const float2*)(blb + min(d, BROWS - 1) * DSTRIDE + cc);
    };
    auto loadL = [&](int d) -> float2 {
        return *(const float2*)(llb + min(d, LROWS - 1) * DSTRIDE + cc);
    };

    constexpr int Q = 4;                // prefetch depth (power of 2)
    float2 qb[Q], ql[Q];
    #pragma unroll
    for (int k = 0; k < Q; ++k) { qb[k] = loadB(k); ql[k] = loadL(k); }

    float prevA = 0.f, prevB = 0.f;

    for (int d = 0; d < ndiag; ++d) {
        const int slot = d & (Q - 1);
        const float2 bl = qb[slot];
        const float2 lb = ql[slot];
        qb[slot] = loadB(d + Q);
        ql[slot] = loadL(d + Q);

        const float upB = __shfl_up(prevB, 1);   // lane i-1's col 2i-1, prev diagonal

        // --- column c0 = 2i ---
        float newA;
        if (lane == 0) {
            newA = (d == 0) ? bl.x : prevA + bl.x;          // u==0: blank-only column
        } else if (d == c0) {                               // t==0: label-only row
            newA = upB + lb.x;
        } else {
            const float a = prevA + bl.x;                   // from (t-1, c0)
            const float c = upB + lb.x;                     // from (t, c0-1)
            const float mx = fmaxf(a, c), mn = fminf(a, c);
            newA = mx + __logf(1.f + __expf(mn - mx));
        }

        // --- column c1 = 2i+1 (u >= 1 always; left neighbor is own c0) ---
        float newB;
        if (d == c1) {                                      // t==0
            newB = prevA + lb.y;                            // alpha[0][c0] from prev diag
        } else {
            const float a = prevB + bl.y;                   // from (t-1, c1)
            const float c = prevA + lb.y;                   // from (t, c0)
            const float mx = fmaxf(a, c), mn = fminf(a, c);
            newB = mx + __logf(1.f + __expf(mn - mx));
        }

        if (d == ndiag - 1) {
            if (c0 == lab) s_loss = -newA;
            if (c1 == lab) s_loss = -newB;
        }
        prevA = newA;
        prevB = newB;
    }

    __syncthreads();
    if (lane == 0) {
        loss_b[b]  = s_loss;
        valid_b[b] = (lab > 0) ? 1 : 0;   // inlen >= 1 always after clip
    }
}

// Kernel 3: mean over valid batch elements.
__global__ void finalize_kernel(const float* __restrict__ loss_b,
                                const int* __restrict__ valid_b,
                                float* __restrict__ out) {
    if (threadIdx.x == 0 && blockIdx.x == 0) {
        float s = 0.f;
        int nv = 0;
        for (int b = 0; b < BB; ++b) {
            if (valid_b[b]) { s += loss_b[b]; ++nv; }
        }
        out[0] = s / (float)max(nv, 1);
    }
}

extern "C" void kernel_launch(void* const* d_in, const int* in_sizes, int n_in,
                              void* d_out, int out_size, void* d_ws, size_t ws_size,
                              hipStream_t stream) {
    const float* logits   = (const float*)d_in[0];
    const int*   labels   = (const int*)d_in[1];
    const int*   lab_lens = (const int*)d_in[2];
    const int*   attn     = (const int*)d_in[3];

    float* ws      = (float*)d_ws;
    float* blankD  = ws;                                   // B * 300 * 102
    float* labD    = blankD + BB * BROWS * DSTRIDE;        // B * 301 * 102
    float* loss_b  = labD   + BB * LROWS * DSTRIDE;        // B
    int*   valid_b = (int*)(loss_b + BB);                  // B

    lse_kernel<<<(NCELL + 3) / 4, 256, 0, stream>>>(logits, labels, blankD, labD);
    alpha_kernel<<<BB, 64, 0, stream>>>(blankD, labD, lab_lens, attn, loss_b, valid_b);
    finalize_kernel<<<1, 64, 0, stream>>>(loss_b, valid_b, (float*)d_out);
}

// Round 3
// 565.827 us; speedup vs baseline: 1.0213x; 1.0213x over previous
//
#include <hip/hip_runtime.h>
#include <hip/hip_bf16.h>
#include <math.h>

#define BB 4
#define TT 200
#define UU 101
#define VV 1024
#define NCELL (BB*TT*UU)   // 80800

// Diagonal-major staging layout (written by lse_kernel, read by alpha_kernel):
//   blankD[b][d][u] = blank_lp(t=d-u, u)   rows d in [0,299], stride 102 (float2-aligned)
//   labD  [b][d][u] = label_lp(t=d-u, u-1) rows d in [0,300], stride 102
#define DSTRIDE 102
#define BROWS 300
#define LROWS 301

typedef float vfloat4 __attribute__((ext_vector_type(4)));

__device__ __forceinline__ float v4max(const vfloat4& v) {
    return fmaxf(fmaxf(v.x, v.y), fmaxf(v.z, v.w));
}
__device__ __forceinline__ float v4comp(const vfloat4& v, int c) {
    switch (c & 3) { case 0: return v.x; case 1: return v.y; case 2: return v.z; default: return v.w; }
}

// Kernel 1: one 64-lane wave per (b,t,u) cell. LSE over V=1024 with nontemporal
// logits loads (331 MB streamed once; keep L2/L3 clean for the staging buffers).
__global__ __launch_bounds__(256) void lse_kernel(
        const float* __restrict__ logits,
        const int*   __restrict__ labels,     // [B, U-1]
        float* __restrict__ blankD,           // [B][300][102]
        float* __restrict__ labD) {           // [B][301][102]
    const int wave = threadIdx.x >> 6;
    const int lane = threadIdx.x & 63;
    const int cell = blockIdx.x * 4 + wave;
    if (cell >= NCELL) return;
    const int b   = cell / (TT * UU);
    const int rem = cell % (TT * UU);
    const int t   = rem / UU;
    const int u   = rem % UU;

    const vfloat4* src = (const vfloat4*)(logits + (size_t)cell * VV);
    vfloat4 x0 = __builtin_nontemporal_load(src + lane);
    vfloat4 x1 = __builtin_nontemporal_load(src + lane + 64);
    vfloat4 x2 = __builtin_nontemporal_load(src + lane + 128);
    vfloat4 x3 = __builtin_nontemporal_load(src + lane + 192);

    float m = fmaxf(fmaxf(v4max(x0), v4max(x1)), fmaxf(v4max(x2), v4max(x3)));
    #pragma unroll
    for (int off = 32; off; off >>= 1) m = fmaxf(m, __shfl_xor(m, off));

    float s = 0.f;
    s += __expf(x0.x - m) + __expf(x0.y - m) + __expf(x0.z - m) + __expf(x0.w - m);
    s += __expf(x1.x - m) + __expf(x1.y - m) + __expf(x1.z - m) + __expf(x1.w - m);
    s += __expf(x2.x - m) + __expf(x2.y - m) + __expf(x2.z - m) + __expf(x2.w - m);
    s += __expf(x3.x - m) + __expf(x3.y - m) + __expf(x3.z - m) + __expf(x3.w - m);
    #pragma unroll
    for (int off = 32; off; off >>= 1) s += __shfl_xor(s, off);

    const float lse = m + __logf(s);

    if (lane == 0)
        blankD[(size_t)b * BROWS * DSTRIDE + (t + u) * DSTRIDE + u] = x0.x - lse;

    if (u < UU - 1) {
        int l = labels[b * (UU - 1) + u];
        l = min(max(l, 0), VV - 1);
        const int lane_l = (l >> 2) & 63;
        if (lane == lane_l) {
            const int j = l >> 8;      // which vfloat4 (0..3)
            const int c = l & 3;       // component
            float val = (j == 0) ? v4comp(x0, c) : (j == 1) ? v4comp(x1, c)
                      : (j == 2) ? v4comp(x2, c) : v4comp(x3, c);
            // label emitted into cell (t, u+1) lies on diagonal t+u+1
            labD[(size_t)b * LROWS * DSTRIDE + (t + u + 1) * DSTRIDE + (u + 1)] = val - lse;
        }
    }
}

// Kernel 2: ONE block of 256 = 4 independent waves, wave w owns batch w.
// Lane i owns columns 2i, 2i+1; one shfl_up per diagonal, hidden under the
// c1-column logaddexp. Q=8 register prefetch queue (coalesced float2 rows).
// Finalize (mean over valid batches) fused after __syncthreads.
__global__ __launch_bounds__(256) void alpha_kernel(
        const float* __restrict__ blankD,
        const float* __restrict__ labD,
        const int*   __restrict__ lab_lens,   // [B]
        const int*   __restrict__ attn,       // [B, T]
        float* __restrict__ out) {            // [1]
    const int b    = threadIdx.x >> 6;
    const int lane = threadIdx.x & 63;

    __shared__ float s_loss[BB];
    __shared__ int   s_lab[BB];

    // input length = clip(sum(attn[b,:]), 1, T)
    int acc = 0;
    for (int i = lane; i < TT; i += 64) acc += attn[b * TT + i];
    #pragma unroll
    for (int off = 32; off; off >>= 1) acc += __shfl_xor(acc, off);
    const int inlen = min(max(acc, 1), TT);
    const int tmax = inlen - 1;
    int lab = lab_lens[b];
    lab = min(max(lab, 0), UU - 1);
    if (lane == 0) s_lab[b] = lab;
    const int ndiag = tmax + lab + 1;   // target cell (tmax, lab) at d = ndiag-1

    const float* blb = blankD + (size_t)b * BROWS * DSTRIDE;
    const float* llb = labD   + (size_t)b * LROWS * DSTRIDE;

    const int c0 = 2 * lane;
    const int c1 = 2 * lane + 1;
    const int cc = min(c0, 100);        // clamp load column (lanes 51..63 inactive)

    auto loadB = [&](int d) -> float2 {
        return *(const float2*)(blb + min(d, BROWS - 1) * DSTRIDE + cc);
    };
    auto loadL = [&](int d) -> float2 {
        return *(const float2*)(llb + min(d, LROWS - 1) * DSTRIDE + cc);
    };

    constexpr int Q = 8;                // prefetch depth (power of 2)
    float2 qb[Q], ql[Q];
    #pragma unroll
    for (int k = 0; k < Q; ++k) { qb[k] = loadB(k); ql[k] = loadL(k); }

    float prevA = 0.f, prevB = 0.f;

    for (int d = 0; d < ndiag; ++d) {
        const int slot = d & (Q - 1);
        const float2 bl = qb[slot];
        const float2 lb = ql[slot];
        qb[slot] = loadB(d + Q);
        ql[slot] = loadL(d + Q);

        const float upB = __shfl_up(prevB, 1);   // lane i-1's col 2i-1, prev diag

        // --- column c1 = 2i+1 first (no shuffle dep; hides shfl latency) ---
        float newB;
        if (d == c1) {                                      // t==0
            newB = prevA + lb.y;                            // alpha[0][c0] from prev diag
        } else {
            const float a = prevB + bl.y;                   // from (t-1, c1)
            const float c = prevA + lb.y;                   // from (t, c0)
            const float mx = fmaxf(a, c), mn = fminf(a, c);
            newB = mx + __logf(1.f + __expf(mn - mx));
        }

        // --- column c0 = 2i ---
        float newA;
        if (lane == 0) {
            newA = (d == 0) ? bl.x : prevA + bl.x;          // u==0: blank-only column
        } else if (d == c0) {                               // t==0: label-only row
            newA = upB + lb.x;
        } else {
            const float a = prevA + bl.x;                   // from (t-1, c0)
            const float c = upB + lb.x;                     // from (t, c0-1)
            const float mx = fmaxf(a, c), mn = fminf(a, c);
            newA = mx + __logf(1.f + __expf(mn - mx));
        }

        if (d == ndiag - 1) {
            if (c0 == lab) s_loss[b] = -newA;
            if (c1 == lab) s_loss[b] = -newB;
        }
        prevA = newA;
        prevB = newB;
    }

    __syncthreads();
    if (threadIdx.x == 0) {
        float s = 0.f;
        int nv = 0;
        #pragma unroll
        for (int i = 0; i < BB; ++i) {
            if (s_lab[i] > 0) { s += s_loss[i]; ++nv; }
        }
        out[0] = s / (float)max(nv, 1);
    }
}

extern "C" void kernel_launch(void* const* d_in, const int* in_sizes, int n_in,
                              void* d_out, int out_size, void* d_ws, size_t ws_size,
                              hipStream_t stream) {
    const float* logits   = (const float*)d_in[0];
    const int*   labels   = (const int*)d_in[1];
    const int*   lab_lens = (const int*)d_in[2];
    const int*   attn     = (const int*)d_in[3];

    float* ws      = (float*)d_ws;
    float* blankD  = ws;                                   // B * 300 * 102
    float* labD    = blankD + BB * BROWS * DSTRIDE;        // B * 301 * 102

    lse_kernel<<<(NCELL + 3) / 4, 256, 0, stream>>>(logits, labels, blankD, labD);
    alpha_kernel<<<1, 256, 0, stream>>>(blankD, labD, lab_lens, attn, (float*)d_out);
}